// Round 6
// baseline (407.992 us; speedup 1.0000x reference)
//
#include <hip/hip_runtime.h>

#define N_NODES 50000
#define N_EDGES 800000
#define F_IN    128
#define NH      4
#define C_OUT   256   // NH*F_OUT

typedef short bf16x8 __attribute__((ext_vector_type(8)));
typedef float f32x4  __attribute__((ext_vector_type(4)));

__device__ __forceinline__ unsigned short f2bf(float f) {
    union { float f; unsigned int u; } v; v.f = f;
    return (unsigned short)((v.u + 0x7FFFu + ((v.u >> 16) & 1u)) >> 16);
}
__device__ __forceinline__ unsigned asu(float f) { union { float f; unsigned u; } v; v.f = f; return v.u; }
__device__ __forceinline__ float asf(unsigned u) { union { unsigned u; float f; } v; v.u = u; return v.f; }

__device__ __forceinline__ void unp8(uint4 u, float* f) {
    f[0] = asf(u.x << 16); f[1] = asf(u.x & 0xffff0000u);
    f[2] = asf(u.y << 16); f[3] = asf(u.y & 0xffff0000u);
    f[4] = asf(u.z << 16); f[5] = asf(u.z & 0xffff0000u);
    f[6] = asf(u.w << 16); f[7] = asf(u.w & 0xffff0000u);
}

// ------- fused: feat f32 -> bf16 copy + nl2[n,h] = sum_f feat^2 * al1^2 (er2 cancels in softmax)
__global__ __launch_bounds__(256) void k_prep(const float* __restrict__ feat,
                                              const float* __restrict__ al1,
                                              unsigned short* __restrict__ fb16,
                                              float* __restrict__ nl2) {
    __shared__ float s_w[512];
    int t = threadIdx.x;
    for (int i = t; i < 512; i += 256) { float a = al1[i]; s_w[i] = a * a; }
    __syncthreads();
    int g = blockIdx.x * 256 + t;
    int n = g >> 2, h = g & 3;
    if (n >= N_NODES) return;
    const float4* f4 = (const float4*)feat;
    uint2* fo = (uint2*)fb16;
    float acc = 0.f;
#pragma unroll 4
    for (int k = 0; k < 32; ++k) {
        float4 v = f4[(size_t)n * 32 + k];
        const float* w = &s_w[h * 128 + k * 4];
        acc += v.x * v.x * w[0] + v.y * v.y * w[1] + v.z * v.z * w[2] + v.w * v.w * w[3];
        if ((k >> 3) == h) {
            unsigned lo = ((unsigned)f2bf(v.y) << 16) | f2bf(v.x);
            unsigned hi = ((unsigned)f2bf(v.w) << 16) | f2bf(v.z);
            fo[(size_t)n * 32 + k] = make_uint2(lo, hi);
        }
    }
    nl2[g] = acc;
}

// ------- fc_w f32 -> bf16
__global__ __launch_bounds__(256) void k_cvtw(const float* __restrict__ fcw,
                                              unsigned short* __restrict__ wb16) {
    int i = blockIdx.x * 256 + threadIdx.x;
    float4 v = ((const float4*)fcw)[i];
    ushort4 o = { f2bf(v.x), f2bf(v.y), f2bf(v.z), f2bf(v.w) };
    ((ushort4*)wb16)[i] = o;
}

// ------- CSR build -------
__global__ void k_deg(const int* __restrict__ dst, int* __restrict__ deg) {
    int e = blockIdx.x * 256 + threadIdx.x;
    if (e < N_EDGES) atomicAdd(&deg[dst[e]], 1);
}
// wave-scan + atomic ticket: off[i] = segment base (placement nondeterministic, contents not)
__global__ __launch_bounds__(256) void k_alloc(const int* __restrict__ deg, int* __restrict__ counter,
                                               int* __restrict__ off, int* __restrict__ fill) {
    int i = blockIdx.x * 256 + threadIdx.x;
    int l = threadIdx.x & 63;
    int x = (i < N_NODES) ? deg[i] : 0;
    int v = x;
#pragma unroll
    for (int o = 1; o < 64; o <<= 1) { int u = __shfl_up(v, o, 64); if (l >= o) v += u; }
    int base = 0;
    if (l == 63) base = atomicAdd(counter, v);
    base = __shfl(base, 63, 64);
    if (i < N_NODES) { int ex = base + v - x; off[i] = ex; fill[i] = ex; }
}
__global__ void k_scatter(const int* __restrict__ src, const int* __restrict__ dst,
                          int* __restrict__ fill, int2* __restrict__ srcdst) {
    int e = blockIdx.x * 256 + threadIdx.x;
    if (e >= N_EDGES) return;
    int d = dst[e];
    int pos = atomicAdd(&fill[d], 1);
    srcdst[pos] = make_int2(src[e], d);
}

// ------- edge scores via MFMA (16 edges/wave-iter) + per-(dst,head) atomicMax
__global__ __launch_bounds__(256) void k_edge(const unsigned short* __restrict__ fb16,
                                              const float* __restrict__ al, const float* __restrict__ ar,
                                              const float* __restrict__ al1, const float* __restrict__ ar1,
                                              const int2* __restrict__ srcdst,
                                              const float* __restrict__ nl2,
                                              float* __restrict__ escore,
                                              unsigned* __restrict__ mbuf) {
    __shared__ unsigned short s_w[512];
    int t = threadIdx.x;
    for (int i = t; i < 512; i += 256)
        s_w[i] = f2bf(al[i] * ar[i] - 2.0f * al1[i] * ar1[i]);
    __syncthreads();
    int lane = t & 63, m = lane & 15, q = lane >> 4;
    int wave = blockIdx.x * 4 + (t >> 6);

    bf16x8 bw[4];
#pragma unroll
    for (int ks = 0; ks < 4; ++ks) {
        if (m < NH) bw[ks] = *(const bf16x8*)&s_w[m * 128 + ks * 32 + q * 8];
        else { bf16x8 z = {0, 0, 0, 0, 0, 0, 0, 0}; bw[ks] = z; }
    }
#pragma unroll
    for (int it = 0; it < 4; ++it) {
        int e0 = (wave * 4 + it) * 16;
        int2 sd = srcdst[e0 + m];
        const uint4* ps = (const uint4*)(fb16 + (size_t)sd.x * 128);
        const uint4* pd = (const uint4*)(fb16 + (size_t)sd.y * 128);
        f32x4 acc = {0.f, 0.f, 0.f, 0.f};
#pragma unroll
        for (int ks = 0; ks < 4; ++ks) {
            uint4 us = ps[ks * 4 + q];
            uint4 ud = pd[ks * 4 + q];
            unsigned c[4] = { us.x, us.y, us.z, us.w };
            unsigned dd[4] = { ud.x, ud.y, ud.z, ud.w };
            union { bf16x8 v; unsigned u[4]; } afr;
#pragma unroll
            for (int j = 0; j < 4; ++j) {
                float a0 = asf(c[j] << 16), a1 = asf(c[j] & 0xffff0000u);
                float b0 = asf(dd[j] << 16), b1 = asf(dd[j] & 0xffff0000u);
                float p0 = a0 * b0, p1 = a1 * b1;
                afr.u[j] = __builtin_amdgcn_perm(asu(p1), asu(p0), 0x07060302u);
            }
            acc = __builtin_amdgcn_mfma_f32_16x16x32_bf16(afr.v, bw[ks], acc, 0, 0, 0);
        }
        if (m < NH) {   // C: col=lane&15 (head), row=q*4+j (edge)
#pragma unroll
            for (int j = 0; j < 4; ++j) {
                int e = e0 + q * 4 + j;
                int2 sd2 = srcdst[e];
                float v = acc[j] + nl2[sd2.x * 4 + m];
                escore[(size_t)e * 4 + m] = v;
                unsigned u = asu(v);
                unsigned key = ((int)u < 0) ? ~u : (u | 0x80000000u);
                atomicMax(&mbuf[sd2.y * 4 + m], key);
            }
        }
    }
}

// ------- aggregation: wave/node, shuffle-free, feat-domain, MFMA projection epilogue
__global__ __launch_bounds__(256) void k_agg(const unsigned short* __restrict__ fb16,
                                             const unsigned short* __restrict__ wb16,
                                             const float* __restrict__ escore,
                                             const int2* __restrict__ srcdst,
                                             const int* __restrict__ off,
                                             const int* __restrict__ degb,
                                             const unsigned* __restrict__ mbuf,
                                             const float* __restrict__ bias,
                                             float* __restrict__ out) {
    __shared__ unsigned short s_af[16 * 136];
    __shared__ float s_bias[256];
    int t = threadIdx.x;
    s_bias[t] = bias[t];
    int w = t >> 6, l = t & 63, h = l & 3, cb = l >> 2;
    int d = blockIdx.x * 4 + w;
    int beg = off[d], deg = degb[d];

    unsigned mk = mbuf[d * 4 + h];
    float m = ((int)mk < 0) ? asf(mk & 0x7FFFFFFFu) : asf(~mk);

    float acc[8] = {0.f, 0.f, 0.f, 0.f, 0.f, 0.f, 0.f, 0.f};
    float den = 0.f;
    const uint4* fp = (const uint4*)fb16;
    for (int j0 = 0; j0 < deg; j0 += 8) {
        int sj[8]; float ej[8];
#pragma unroll
        for (int k = 0; k < 8; ++k) {
            int j = j0 + k; if (j > deg - 1) j = deg - 1;
            int e = beg + j;
            sj[k] = srcdst[e].x;
            ej[k] = escore[(size_t)e * 4 + h];
        }
        uint4 u[8];
#pragma unroll
        for (int k = 0; k < 8; ++k)
            u[k] = fp[(size_t)sj[k] * 16 + cb];
#pragma unroll
        for (int k = 0; k < 8; ++k) {
            float ex = (j0 + k < deg) ? __expf(ej[k] - m) : 0.f;
            den += ex;
            float f[8]; unp8(u[k], f);
#pragma unroll
            for (int j = 0; j < 8; ++j) acc[j] = fmaf(ex, f[j], acc[j]);
        }
    }

    float inv = (den > 0.f) ? 1.0f / den : 0.f;
    {
        unsigned o0 = ((unsigned)f2bf(acc[1] * inv) << 16) | f2bf(acc[0] * inv);
        unsigned o1 = ((unsigned)f2bf(acc[3] * inv) << 16) | f2bf(acc[2] * inv);
        unsigned o2 = ((unsigned)f2bf(acc[5] * inv) << 16) | f2bf(acc[4] * inv);
        unsigned o3 = ((unsigned)f2bf(acc[7] * inv) << 16) | f2bf(acc[6] * inv);
        *(uint4*)&s_af[(w * 4 + h) * 136 + cb * 8] = make_uint4(o0, o1, o2, o3);
    }
    __syncthreads();

    // epilogue: wave w owns output col-tile w; A rows = node*4+head
    int n = l & 15, q = l >> 4;
    bf16x8 afr[4];
#pragma unroll
    for (int step = 0; step < 4; ++step)
        afr[step] = *(const bf16x8*)&s_af[n * 136 + step * 32 + q * 8];

    f32x4 c[4] = {};
#pragma unroll
    for (int h4 = 0; h4 < 4; ++h4) {
#pragma unroll
        for (int step = 0; step < 4; ++step) {
            union { uint4 u; bf16x8 v; } b;
            b.u = *(const uint4*)(wb16 + (size_t)(h4 * 64 + w * 16 + n) * 128 + step * 32 + q * 8);
            c[h4] = __builtin_amdgcn_mfma_f32_16x16x32_bf16(afr[step], b.v, c[h4], 0, 0, 0);
        }
    }
    int node = blockIdx.x * 4 + q;   // C row = q*4+j; j=h4 -> node q, head h4
#pragma unroll
    for (int h4 = 0; h4 < 4; ++h4)
        out[(size_t)node * 256 + h4 * 64 + w * 16 + n] = c[h4][h4] + s_bias[h4 * 64 + w * 16 + n];
}

extern "C" void kernel_launch(void* const* d_in, const int* in_sizes, int n_in,
                              void* d_out, int out_size, void* d_ws, size_t ws_size,
                              hipStream_t stream) {
    const float* feat = (const float*)d_in[0];
    const int*   src  = (const int*)d_in[1];
    const int*   dst  = (const int*)d_in[2];
    const float* fcw  = (const float*)d_in[3];
    const float* al   = (const float*)d_in[4];
    const float* ar   = (const float*)d_in[5];
    const float* al1  = (const float*)d_in[6];
    const float* ar1  = (const float*)d_in[7];
    const float* bias = (const float*)d_in[8];
    float* out = (float*)d_out;

    char* ws = (char*)d_ws;
    size_t o = 0;
    auto take = [&](size_t b) -> void* {
        void* p = ws + o;
        o = (o + b + 255) & ~(size_t)255;
        return p;
    };
    unsigned short* fb16 = (unsigned short*)take((size_t)N_NODES * F_IN * 2);  // 12.8 MB
    unsigned short* wb16 = (unsigned short*)take((size_t)C_OUT * F_IN * 2);    // 64 KB
    float*    nl2    = (float*)take((size_t)N_NODES * 4 * 4);
    float*    escore = (float*)take((size_t)N_EDGES * 4 * 4);                  // 12.8 MB
    int2*     srcdst = (int2*)take((size_t)N_EDGES * 8);                       // 6.4 MB
    // packed zero-region: deg | mbuf | counter  (one memset)
    int* zr = (int*)take((size_t)(N_NODES + N_NODES * 4 + 64) * 4);
    int*      deg     = zr;
    unsigned* mbuf    = (unsigned*)(zr + N_NODES);
    int*      counter = zr + N_NODES + N_NODES * 4;
    int* off  = (int*)take((size_t)N_NODES * 4);
    int* fill = (int*)take((size_t)N_NODES * 4);

    hipMemsetAsync(zr, 0, (size_t)(N_NODES + N_NODES * 4 + 64) * 4, stream);
    k_prep<<<782, 256, 0, stream>>>(feat, al1, fb16, nl2);
    k_cvtw<<<32, 256, 0, stream>>>(fcw, wb16);
    k_deg<<<(N_EDGES + 255) / 256, 256, 0, stream>>>(dst, deg);
    k_alloc<<<(N_NODES + 255) / 256, 256, 0, stream>>>(deg, counter, off, fill);
    k_scatter<<<(N_EDGES + 255) / 256, 256, 0, stream>>>(src, dst, fill, srcdst);
    k_edge<<<3125, 256, 0, stream>>>(fb16, al, ar, al1, ar1, srcdst, nl2, escore, mbuf);
    k_agg<<<N_NODES / 4, 256, 0, stream>>>(fb16, wb16, escore, srcdst, off, deg, mbuf, bias, out);
}

// Round 7
// 382.485 us; speedup vs baseline: 1.0667x; 1.0667x over previous
//
#include <hip/hip_runtime.h>

#define N_NODES 50000
#define N_EDGES 800000
#define F_IN    128
#define NH      4
#define C_OUT   256   // NH*F_OUT

typedef short bf16x8 __attribute__((ext_vector_type(8)));
typedef float f32x4  __attribute__((ext_vector_type(4)));

__device__ __forceinline__ unsigned short f2bf(float f) {
    union { float f; unsigned int u; } v; v.f = f;
    return (unsigned short)((v.u + 0x7FFFu + ((v.u >> 16) & 1u)) >> 16);
}
__device__ __forceinline__ unsigned asu(float f) { union { float f; unsigned u; } v; v.f = f; return v.u; }
__device__ __forceinline__ float asf(unsigned u) { union { unsigned u; float f; } v; v.u = u; return v.f; }

// ------- fused: feat f32 -> bf16 copy + nl2[n,h] = sum_f feat^2 * al1^2 (er2 cancels in softmax)
__global__ __launch_bounds__(256) void k_prep(const float* __restrict__ feat,
                                              const float* __restrict__ al1,
                                              unsigned short* __restrict__ fb16,
                                              float* __restrict__ nl2) {
    __shared__ float s_w[512];
    int t = threadIdx.x;
    for (int i = t; i < 512; i += 256) { float a = al1[i]; s_w[i] = a * a; }
    __syncthreads();
    int g = blockIdx.x * 256 + t;
    int n = g >> 2, h = g & 3;
    if (n >= N_NODES) return;
    const float4* f4 = (const float4*)feat;
    uint2* fo = (uint2*)fb16;
    float acc = 0.f;
#pragma unroll 4
    for (int k = 0; k < 32; ++k) {
        float4 v = f4[(size_t)n * 32 + k];
        const float* w = &s_w[h * 128 + k * 4];
        acc += v.x * v.x * w[0] + v.y * v.y * w[1] + v.z * v.z * w[2] + v.w * v.w * w[3];
        if ((k >> 3) == h) {
            unsigned lo = ((unsigned)f2bf(v.y) << 16) | f2bf(v.x);
            unsigned hi = ((unsigned)f2bf(v.w) << 16) | f2bf(v.z);
            fo[(size_t)n * 32 + k] = make_uint2(lo, hi);
        }
    }
    nl2[g] = acc;
}

// ------- fc_w f32 -> bf16
__global__ __launch_bounds__(256) void k_cvtw(const float* __restrict__ fcw,
                                              unsigned short* __restrict__ wb16) {
    int i = blockIdx.x * 256 + threadIdx.x;
    float4 v = ((const float4*)fcw)[i];
    ushort4 o = { f2bf(v.x), f2bf(v.y), f2bf(v.z), f2bf(v.w) };
    ((ushort4*)wb16)[i] = o;
}

// ------- CSR build -------
__global__ void k_deg(const int* __restrict__ dst, int* __restrict__ deg) {
    int e = blockIdx.x * 256 + threadIdx.x;
    if (e < N_EDGES) atomicAdd(&deg[dst[e]], 1);
}
__global__ __launch_bounds__(256) void k_alloc(const int* __restrict__ deg, int* __restrict__ counter,
                                               int* __restrict__ off, int* __restrict__ fill) {
    int i = blockIdx.x * 256 + threadIdx.x;
    int l = threadIdx.x & 63;
    int x = (i < N_NODES) ? deg[i] : 0;
    int v = x;
#pragma unroll
    for (int o = 1; o < 64; o <<= 1) { int u = __shfl_up(v, o, 64); if (l >= o) v += u; }
    int base = 0;
    if (l == 63) base = atomicAdd(counter, v);
    base = __shfl(base, 63, 64);
    if (i < N_NODES) { int ex = base + v - x; off[i] = ex; fill[i] = ex; }
}
__global__ void k_scatter(const int* __restrict__ src, const int* __restrict__ dst,
                          int* __restrict__ fill, int* __restrict__ esrc, int* __restrict__ edst) {
    int e = blockIdx.x * 256 + threadIdx.x;
    if (e >= N_EDGES) return;
    int d = dst[e];
    int pos = atomicAdd(&fill[d], 1);
    esrc[pos] = src[e];
    edst[pos] = d;
}

// ------- edge scores via MFMA (16 edges/wave-iter), dup-free gathers
__global__ __launch_bounds__(256) void k_edge(const unsigned short* __restrict__ fb16,
                                              const float* __restrict__ al, const float* __restrict__ ar,
                                              const float* __restrict__ al1, const float* __restrict__ ar1,
                                              const int* __restrict__ esrc,
                                              const int* __restrict__ edst,
                                              const float* __restrict__ nl2,
                                              float* __restrict__ escore) {
    __shared__ unsigned short s_w[512];
    int t = threadIdx.x;
    for (int i = t; i < 512; i += 256)
        s_w[i] = f2bf(al[i] * ar[i] - 2.0f * al1[i] * ar1[i]);
    __syncthreads();
    int lane = t & 63, m = lane & 15, q = lane >> 4;
    int wave = blockIdx.x * 4 + (t >> 6);

    bf16x8 bw[4];
#pragma unroll
    for (int ks = 0; ks < 4; ++ks) {
        if (m < NH) bw[ks] = *(const bf16x8*)&s_w[m * 128 + ks * 32 + q * 8];
        else { bf16x8 z = {0, 0, 0, 0, 0, 0, 0, 0}; bw[ks] = z; }
    }
#pragma unroll
    for (int it = 0; it < 4; ++it) {
        int e0 = (wave * 4 + it) * 16;
        int s = esrc[e0 + m];
        int dd = edst[e0 + m];
        const uint4* ps = (const uint4*)(fb16 + (size_t)s * 128);
        const uint4* pd = (const uint4*)(fb16 + (size_t)dd * 128);
        f32x4 acc = {0.f, 0.f, 0.f, 0.f};
#pragma unroll
        for (int ks = 0; ks < 4; ++ks) {
            uint4 us = ps[ks * 4 + q];
            uint4 ud = pd[ks * 4 + q];
            unsigned c[4] = { us.x, us.y, us.z, us.w };
            unsigned dv[4] = { ud.x, ud.y, ud.z, ud.w };
            union { bf16x8 v; unsigned u[4]; } afr;
#pragma unroll
            for (int j = 0; j < 4; ++j) {
                float a0 = asf(c[j] << 16), a1 = asf(c[j] & 0xffff0000u);
                float b0 = asf(dv[j] << 16), b1 = asf(dv[j] & 0xffff0000u);
                float p0 = a0 * b0, p1 = a1 * b1;
                afr.u[j] = __builtin_amdgcn_perm(asu(p1), asu(p0), 0x07060302u);
            }
            acc = __builtin_amdgcn_mfma_f32_16x16x32_bf16(afr.v, bw[ks], acc, 0, 0, 0);
        }
        if (m < NH) {   // C: col=lane&15 (head), row=q*4+j (edge)
#pragma unroll
            for (int j = 0; j < 4; ++j) {
                int e = e0 + q * 4 + j;
                int s2 = esrc[e];
                escore[(size_t)e * 4 + m] = acc[j] + nl2[s2 * 4 + m];
            }
        }
    }
}

// ------- aggregation: wave/node, dup-free dword gathers (lane = col pair, all 4 heads),
//         no-max softmax, MFMA projection epilogue
__global__ __launch_bounds__(256) void k_agg(const unsigned short* __restrict__ fb16,
                                             const unsigned short* __restrict__ wb16,
                                             const float* __restrict__ escore,
                                             const int* __restrict__ esrc,
                                             const int* __restrict__ off,
                                             const int* __restrict__ degb,
                                             const float* __restrict__ bias,
                                             float* __restrict__ out) {
    __shared__ unsigned short s_af[16 * 136];
    __shared__ float s_bias[256];
    int t = threadIdx.x;
    s_bias[t] = bias[t];
    int w = t >> 6, l = t & 63;
    int d = blockIdx.x * 4 + w;
    int beg = off[d], deg = degb[d];

    float acc0[4] = {0.f, 0.f, 0.f, 0.f};  // col 2l,   heads 0..3
    float acc1[4] = {0.f, 0.f, 0.f, 0.f};  // col 2l+1, heads 0..3
    float den[4]  = {0.f, 0.f, 0.f, 0.f};
    const unsigned* fp = (const unsigned*)fb16;   // dword view (2 bf16)
    const float4* ep = (const float4*)escore;

    for (int j0 = 0; j0 < deg; j0 += 4) {
        int sj[4]; float4 ej[4];
#pragma unroll
        for (int k = 0; k < 4; ++k) {
            int j = j0 + k; if (j > deg - 1) j = deg - 1;
            sj[k] = esrc[beg + j];
            ej[k] = ep[beg + j];
        }
        unsigned u[4];
#pragma unroll
        for (int k = 0; k < 4; ++k)
            u[k] = fp[(size_t)sj[k] * 64 + l];
#pragma unroll
        for (int k = 0; k < 4; ++k) {
            bool live = (j0 + k < deg);
            float e0 = live ? __expf(ej[k].x) : 0.f;
            float e1 = live ? __expf(ej[k].y) : 0.f;
            float e2 = live ? __expf(ej[k].z) : 0.f;
            float e3 = live ? __expf(ej[k].w) : 0.f;
            float f0 = asf(u[k] << 16), f1 = asf(u[k] & 0xffff0000u);
            den[0] += e0; den[1] += e1; den[2] += e2; den[3] += e3;
            acc0[0] = fmaf(e0, f0, acc0[0]); acc1[0] = fmaf(e0, f1, acc1[0]);
            acc0[1] = fmaf(e1, f0, acc0[1]); acc1[1] = fmaf(e1, f1, acc1[1]);
            acc0[2] = fmaf(e2, f0, acc0[2]); acc1[2] = fmaf(e2, f1, acc1[2]);
            acc0[3] = fmaf(e3, f0, acc0[3]); acc1[3] = fmaf(e3, f1, acc1[3]);
        }
    }

#pragma unroll
    for (int h = 0; h < 4; ++h) {
        float inv = (den[h] > 0.f) ? 1.0f / den[h] : 0.f;
        unsigned pk = ((unsigned)f2bf(acc1[h] * inv) << 16) | f2bf(acc0[h] * inv);
        *(unsigned*)&s_af[(w * 4 + h) * 136 + 2 * l] = pk;
    }
    __syncthreads();

    // epilogue: wave w owns output col-tile w; A rows = node_in_block*4+head
    int n = l & 15, q = l >> 4;
    bf16x8 afr[4];
#pragma unroll
    for (int step = 0; step < 4; ++step)
        afr[step] = *(const bf16x8*)&s_af[n * 136 + step * 32 + q * 8];

    f32x4 c[4] = {};
#pragma unroll
    for (int h4 = 0; h4 < 4; ++h4) {
#pragma unroll
        for (int step = 0; step < 4; ++step) {
            union { uint4 u; bf16x8 v; } b;
            b.u = *(const uint4*)(wb16 + (size_t)(h4 * 64 + w * 16 + n) * 128 + step * 32 + q * 8);
            c[h4] = __builtin_amdgcn_mfma_f32_16x16x32_bf16(afr[step], b.v, c[h4], 0, 0, 0);
        }
    }
    int node = blockIdx.x * 4 + q;   // C row = q*4+j; j=h4 -> node q, head h4
#pragma unroll
    for (int h4 = 0; h4 < 4; ++h4)
        out[(size_t)node * 256 + h4 * 64 + w * 16 + n] = c[h4][h4] + s_bias[h4 * 64 + w * 16 + n];
}

extern "C" void kernel_launch(void* const* d_in, const int* in_sizes, int n_in,
                              void* d_out, int out_size, void* d_ws, size_t ws_size,
                              hipStream_t stream) {
    const float* feat = (const float*)d_in[0];
    const int*   src  = (const int*)d_in[1];
    const int*   dst  = (const int*)d_in[2];
    const float* fcw  = (const float*)d_in[3];
    const float* al   = (const float*)d_in[4];
    const float* ar   = (const float*)d_in[5];
    const float* al1  = (const float*)d_in[6];
    const float* ar1  = (const float*)d_in[7];
    const float* bias = (const float*)d_in[8];
    float* out = (float*)d_out;

    char* ws = (char*)d_ws;
    size_t o = 0;
    auto take = [&](size_t b) -> void* {
        void* p = ws + o;
        o = (o + b + 255) & ~(size_t)255;
        return p;
    };
    unsigned short* fb16 = (unsigned short*)take((size_t)N_NODES * F_IN * 2);  // 12.8 MB
    unsigned short* wb16 = (unsigned short*)take((size_t)C_OUT * F_IN * 2);    // 64 KB
    float* nl2    = (float*)take((size_t)N_NODES * 4 * 4);
    float* escore = (float*)take((size_t)N_EDGES * 4 * 4);                     // 12.8 MB
    int*   esrc   = (int*)take((size_t)N_EDGES * 4);                           // 3.2 MB
    int*   edst   = (int*)take((size_t)N_EDGES * 4);                           // 3.2 MB
    // packed zero-region: deg | counter  (one memset)
    int* zr = (int*)take((size_t)(N_NODES + 64) * 4);
    int* deg     = zr;
    int* counter = zr + N_NODES;
    int* off  = (int*)take((size_t)N_NODES * 4);
    int* fill = (int*)take((size_t)N_NODES * 4);

    hipMemsetAsync(zr, 0, (size_t)(N_NODES + 64) * 4, stream);
    k_prep<<<782, 256, 0, stream>>>(feat, al1, fb16, nl2);
    k_cvtw<<<32, 256, 0, stream>>>(fcw, wb16);
    k_deg<<<(N_EDGES + 255) / 256, 256, 0, stream>>>(dst, deg);
    k_alloc<<<(N_NODES + 255) / 256, 256, 0, stream>>>(deg, counter, off, fill);
    k_scatter<<<(N_EDGES + 255) / 256, 256, 0, stream>>>(src, dst, fill, esrc, edst);
    k_edge<<<3125, 256, 0, stream>>>(fb16, al, ar, al1, ar1, esrc, edst, nl2, escore);
    k_agg<<<N_NODES / 4, 256, 0, stream>>>(fb16, wb16, escore, esrc, off, deg, bias, out);
}